// Round 5
// baseline (2073.705 us; speedup 1.0000x reference)
//
#include <hip/hip_runtime.h>
#include <stdint.h>
#include <math.h>

typedef short short8 __attribute__((ext_vector_type(8)));
typedef float floatx4 __attribute__((ext_vector_type(4)));

#define MFMA(a, b, c) __builtin_amdgcn_mfma_f32_16x16x32_bf16((a), (b), (c), 0, 0, 0)

#define B_   64
#define S_   256
#define DIN  512
#define DH   1024
#define G3   3072
#define DOUT 64
#define M_   (B_ * S_)  // 16384
#define NBLK 128        // persistent blocks: 64 col-chunks x 2 batch halves
#define NFLAG (S_ * 2 * 64)  // per-(step, mh, jc) ready flags

#define AGENT_LD_U64(p) __hip_atomic_load((p), __ATOMIC_RELAXED, __HIP_MEMORY_SCOPE_AGENT)
#define AGENT_LD_U32(p) __hip_atomic_load((p), __ATOMIC_RELAXED, __HIP_MEMORY_SCOPE_AGENT)
#define AGENT_ST_U32(p, v) __hip_atomic_store((p), (v), __ATOMIC_RELAXED, __HIP_MEMORY_SCOPE_AGENT)

__device__ __forceinline__ unsigned short f2bf(float f) {
    union { float f; uint32_t u; } v; v.f = f;
    uint32_t u = v.u;
    uint32_t r = (u + 0x7fffu + ((u >> 16) & 1u)) >> 16;  // RNE
    return (unsigned short)r;
}
__device__ __forceinline__ float bf2f(unsigned short s) {
    union { uint32_t u; float f; } v; v.u = ((uint32_t)s) << 16; return v.f;
}
__device__ __forceinline__ short8 ld8(const unsigned short* p) {
    return *reinterpret_cast<const short8*>(p);
}
__device__ __forceinline__ float fast_sigmoid(float x) {
    return 1.f / (1.f + __expf(-x));
}
__device__ __forceinline__ float fast_tanh(float x) {
    return 1.f - 2.f / (__expf(2.f * x) + 1.f);
}

// ---------------- elementwise: fp32 -> bf16 cast ----------------
__global__ void cast_bf16_kernel(const float* __restrict__ src,
                                 unsigned short* __restrict__ dst, int n) {
    int i = blockIdx.x * 256 + threadIdx.x;
    if (i < n) dst[i] = f2bf(src[i]);
}

// ---------------- zero the flag region (ws is poisoned 0xAA!) ----------------
__global__ void init_flags_kernel(unsigned int* flags) {
    int i = blockIdx.x * 256 + threadIdx.x;
    if (i < NFLAG) flags[i] = 0u;
}

// ---------------- embedding gather into [s*64+b][512] bf16 ----------------
__global__ void gather_kernel(const int* __restrict__ x, const float* __restrict__ emb,
                              unsigned short* __restrict__ xe) {
    int g = blockIdx.x * 256 + threadIdx.x;  // 16384*512 total
    int m = g >> 9;          // row = s*64+b
    int k = g & 511;
    int s = m >> 6, b = m & 63;
    int tok = x[b * S_ + s];
    xe[(size_t)m * DIN + k] = f2bf(emb[(size_t)tok * DIN + k]);
}

// ---------------- bt-GEMM: C[M,N] bf16 = A[M,K] @ W[N,K]^T + bias ----------------
__global__ __launch_bounds__(256) void gemm_bt_bias(
        const unsigned short* __restrict__ A, const unsigned short* __restrict__ W,
        const float* __restrict__ bias, unsigned short* __restrict__ C,
        int M, int N, int K) {
    __shared__ __align__(16) unsigned short As[128 * 32];
    __shared__ __align__(16) unsigned short Ws[128 * 32];
    int tid = threadIdx.x;
    int lane = tid & 63, wv = tid >> 6;
    int wm = wv >> 1, wn = wv & 1;
    int q = lane >> 4, l15 = lane & 15;
    int bm = blockIdx.x, bn = blockIdx.y;

    floatx4 acc[4][4];
    floatx4 z = {0.f, 0.f, 0.f, 0.f};
    for (int i = 0; i < 4; i++) for (int j = 0; j < 4; j++) acc[i][j] = z;

    int row_s = tid >> 1;
    int col_s = (tid & 1) * 16;
    const unsigned short* Ab = A + (size_t)(bm * 128 + row_s) * K + col_s;
    const unsigned short* Wb = W + (size_t)(bn * 128 + row_s) * K + col_s;
    unsigned short* AsW = &As[row_s * 32 + col_s];
    unsigned short* WsW = &Ws[row_s * 32 + col_s];

    for (int k0 = 0; k0 < K; k0 += 32) {
        __syncthreads();
        *reinterpret_cast<short8*>(AsW)     = ld8(Ab + k0);
        *reinterpret_cast<short8*>(AsW + 8) = ld8(Ab + k0 + 8);
        *reinterpret_cast<short8*>(WsW)     = ld8(Wb + k0);
        *reinterpret_cast<short8*>(WsW + 8) = ld8(Wb + k0 + 8);
        __syncthreads();
        short8 af[4], wf[4];
        for (int t = 0; t < 4; t++) {
            af[t] = ld8(&As[(wm * 64 + t * 16 + l15) * 32 + q * 8]);
            wf[t] = ld8(&Ws[(wn * 64 + t * 16 + l15) * 32 + q * 8]);
        }
        for (int i = 0; i < 4; i++)
            for (int j = 0; j < 4; j++)
                acc[i][j] = MFMA(af[i], wf[j], acc[i][j]);
    }
    for (int i = 0; i < 4; i++) {
        int row = bm * 128 + wm * 64 + i * 16 + q * 4;
        for (int j = 0; j < 4; j++) {
            int col = bn * 128 + wn * 64 + j * 16 + l15;
            float bv = bias[col];
            for (int r = 0; r < 4; r++)
                C[(size_t)(row + r) * N + col] = f2bf(acc[i][j][r] + bv);
        }
    }
}

// ---------------- persistent GRU recurrence (dataflow flags, no grid barrier) ---
// 128 blocks x 512 thr (8 waves). Block = (jc: 16 h-cols, all 3 gates) x (mh: 32
// batch rows). Wave = (mt: 16-row tile) x (kh: 256-wide K quarter).
// whh frags register-resident (96 VGPR). h carried fp32 in gate-wave regs.
// Sync: producer block sets flags[s][mh][jc] after its hs stores are ack'd
// (vmcnt drain at __syncthreads); consumer wave kh polls only the 16 flags of
// its K quarter (one coalesced 16-word read per iteration). No fences anywhere.
__global__ __launch_bounds__(512, 2) void gru_persistent(
        const unsigned short* __restrict__ gi,   // [256][64][3072] bf16 (incl b_ih)
        const unsigned short* __restrict__ whh,  // [3072][1024] bf16
        const float* __restrict__ b_hh,          // [3072]
        unsigned short* __restrict__ hs,         // [256][64][1024] bf16
        unsigned int* flags) {                   // [256][2][64] ready flags
    const int tid = threadIdx.x;
    const int lane = tid & 63, wv = tid >> 6;
    const int mt = wv & 1, kh = wv >> 1;         // kh 0..3
    const int q = lane >> 4, l15 = lane & 15;
    const int jc = blockIdx.x >> 1, mh = blockIdx.x & 1;
    const int j = jc * 16 + l15;                 // h-col 0..1023
    const int brow0 = mh * 32 + mt * 16;         // wave's 16 batch rows

    __shared__ float red[3][2][3][4][64];        // [kh-1][mt][g][r][lane] = 18 KB

    // ---- register-resident weight fragments: rows {j, 1024+j, 2048+j}, K quarter kh ----
    short8 wfrag[3][8];
#pragma unroll
    for (int g = 0; g < 3; g++)
#pragma unroll
        for (int kk = 0; kk < 8; kk++)
            wfrag[g][kk] = ld8(whh + (size_t)(g * 1024 + j) * DH + kh * 256 + kk * 32 + q * 8);

    float bhr = 0.f, bhz = 0.f, bhn = 0.f;
    float hreg[4];
    float gir[4], giz[4], gin[4];
    if (kh == 0) {
        bhr = b_hh[j]; bhz = b_hh[1024 + j]; bhn = b_hh[2048 + j];
#pragma unroll
        for (int r = 0; r < 4; r++) {
            hreg[r] = 0.f;
            int b = brow0 + q * 4 + r;           // initial gi prefetch (s=0)
            gir[r] = bf2f(gi[(size_t)b * G3 + j]);
            giz[r] = bf2f(gi[(size_t)b * G3 + 1024 + j]);
            gin[r] = bf2f(gi[(size_t)b * G3 + 2048 + j]);
        }
    }

    for (int s = 0; s < S_; s++) {
        // ---- MFMA phase: gh partials for this K quarter ----
        floatx4 zf = {0.f, 0.f, 0.f, 0.f};
        floatx4 acc[3] = {zf, zf, zf};
        if (s > 0) {
            // wait for the 16 producer blocks of my K quarter (step s-1, my mh half)
            const unsigned int* fp =
                flags + (((s - 1) << 1) + mh) * 64 + kh * 16 + l15;
            while (!__all(AGENT_LD_U32(fp) != 0u)) {}
            asm volatile("" ::: "memory");

            const uint64_t* hp = (const uint64_t*)hs +
                (((size_t)(s - 1) * B_ + (brow0 + l15)) * DH + kh * 256 + q * 8) / 4;
#pragma unroll
            for (int kk = 0; kk < 8; kk++) {
                union { uint64_t u[2]; short8 v; } cvt;
                cvt.u[0] = AGENT_LD_U64(hp + kk * 8);
                cvt.u[1] = AGENT_LD_U64(hp + kk * 8 + 1);
                short8 a = cvt.v;
#pragma unroll
                for (int g = 0; g < 3; g++)
                    acc[g] = MFMA(a, wfrag[g][kk], acc[g]);
            }
        }

        // ---- cross-wave K reduction ----
        if (kh > 0) {
#pragma unroll
            for (int g = 0; g < 3; g++)
#pragma unroll
                for (int r = 0; r < 4; r++)
                    red[kh - 1][mt][g][r][lane] = acc[g][r];
        }
        __syncthreads();

        // ---- gate phase (the two kh==0 waves) ----
        if (kh == 0) {
#pragma unroll
            for (int p = 0; p < 3; p++)
#pragma unroll
                for (int g = 0; g < 3; g++)
#pragma unroll
                    for (int r = 0; r < 4; r++)
                        acc[g][r] += red[p][mt][g][r][lane];
            uint32_t* ho32 = (uint32_t*)(hs + (size_t)s * B_ * DH);
#pragma unroll
            for (int r = 0; r < 4; r++) {
                int b = brow0 + q * 4 + r;
                float rg = fast_sigmoid(gir[r] + acc[0][r] + bhr);
                float zg = fast_sigmoid(giz[r] + acc[1][r] + bhz);
                float ng = fast_tanh(gin[r] + rg * (acc[2][r] + bhn));
                float h = (1.f - zg) * ng + zg * hreg[r];
                hreg[r] = h;
                // pack bf16 pair across adjacent lanes (cols j, j+1), even lane stores u32
                float hnb = __shfl_xor(h, 1);
                if ((l15 & 1) == 0) {
                    uint32_t pk = (uint32_t)f2bf(h) | ((uint32_t)f2bf(hnb) << 16);
                    AGENT_ST_U32(&ho32[((size_t)b * DH + j) >> 1], pk);
                }
            }
            // prefetch gi for s+1 (overlaps consumer polling elsewhere)
            if (s + 1 < S_) {
                const unsigned short* gp = gi + (size_t)(s + 1) * B_ * G3;
#pragma unroll
                for (int r = 0; r < 4; r++) {
                    int b = brow0 + q * 4 + r;
                    gir[r] = bf2f(gp[(size_t)b * G3 + j]);
                    giz[r] = bf2f(gp[(size_t)b * G3 + 1024 + j]);
                    gin[r] = bf2f(gp[(size_t)b * G3 + 2048 + j]);
                }
            }
        }
        if (s + 1 == S_) break;
        // drains each wave's vmcnt (incl. gate-wave hs stores) before s_barrier
        __syncthreads();
        // publish: this block's h slice for step s is globally visible
        if (tid == 0)
            AGENT_ST_U32(&flags[((s << 1) + mh) * 64 + jc], 1u);
    }
}

// ---------------- FC + log_softmax, fused ----------------
__global__ __launch_bounds__(256) void fc_logsoftmax(
        const unsigned short* __restrict__ hs,    // [16384][1024] bf16, row = s*64+b
        const unsigned short* __restrict__ fcw,   // [64][1024] bf16
        const float* __restrict__ fcb,            // [64]
        float* __restrict__ out) {                // [B][S][64]
    int tid = threadIdx.x;
    int lane = tid & 63, mt = tid >> 6;
    int q = lane >> 4, l15 = lane & 15;
    int r0 = blockIdx.x * 64;

    floatx4 acc[4];
    floatx4 z = {0.f, 0.f, 0.f, 0.f};
    for (int nt = 0; nt < 4; nt++) acc[nt] = z;

    const unsigned short* Ap = hs + (size_t)(r0 + mt * 16 + l15) * DH + q * 8;
    const unsigned short* Wp = fcw + (size_t)l15 * DH + q * 8;
    for (int k0 = 0; k0 < DH; k0 += 32) {
        short8 a = ld8(Ap + k0);
        for (int nt = 0; nt < 4; nt++)
            acc[nt] = MFMA(a, ld8(Wp + (size_t)nt * 16 * DH + k0), acc[nt]);
    }

    float bv[4];
    for (int nt = 0; nt < 4; nt++) bv[nt] = fcb[nt * 16 + l15];

    for (int r = 0; r < 4; r++) {
        float v[4];
        for (int nt = 0; nt < 4; nt++) v[nt] = acc[nt][r] + bv[nt];
        float m = fmaxf(fmaxf(v[0], v[1]), fmaxf(v[2], v[3]));
        for (int off = 1; off < 16; off <<= 1) m = fmaxf(m, __shfl_xor(m, off));
        float se = __expf(v[0] - m) + __expf(v[1] - m) + __expf(v[2] - m) + __expf(v[3] - m);
        for (int off = 1; off < 16; off <<= 1) se += __shfl_xor(se, off);
        float L = logf(se);
        int row = r0 + mt * 16 + q * 4 + r;  // = s*64 + b
        int srow = row >> 6, brow = row & 63;
        float* op = out + (size_t)(brow * S_ + srow) * DOUT;
        for (int nt = 0; nt < 4; nt++) op[nt * 16 + l15] = v[nt] - m - L;
    }
}

extern "C" void kernel_launch(void* const* d_in, const int* in_sizes, int n_in,
                              void* d_out, int out_size, void* d_ws, size_t ws_size,
                              hipStream_t stream) {
    const int*   x    = (const int*)d_in[0];
    const float* emb  = (const float*)d_in[1];
    const float* w_ih = (const float*)d_in[2];
    const float* w_hh = (const float*)d_in[3];
    const float* b_ih = (const float*)d_in[4];
    const float* b_hh = (const float*)d_in[5];
    const float* fc_w = (const float*)d_in[6];
    const float* fc_b = (const float*)d_in[7];
    float* out = (float*)d_out;

    char* p = (char*)d_ws;
    unsigned int*   flags = (unsigned int*)p;   p += NFLAG * 4;              // 128 KB
    unsigned short* xe    = (unsigned short*)p; p += (size_t)M_ * DIN * 2;   // 16 MB
    unsigned short* gi    = (unsigned short*)p; p += (size_t)M_ * G3 * 2;    // 100.7 MB
    unsigned short* wih_b = (unsigned short*)p; p += (size_t)G3 * DIN * 2;   // 3 MB
    unsigned short* whh_b = (unsigned short*)p; p += (size_t)G3 * DH * 2;    // 6.3 MB
    unsigned short* fcw_b = (unsigned short*)p; p += (size_t)DOUT * DH * 2;  // 128 KB
    unsigned short* hs    = (unsigned short*)p; p += (size_t)M_ * DH * 2;    // 33.6 MB

    init_flags_kernel<<<(NFLAG + 255) / 256, 256, 0, stream>>>(flags);
    cast_bf16_kernel<<<(G3 * DIN + 255) / 256, 256, 0, stream>>>(w_ih, wih_b, G3 * DIN);
    cast_bf16_kernel<<<(G3 * DH + 255) / 256, 256, 0, stream>>>(w_hh, whh_b, G3 * DH);
    cast_bf16_kernel<<<(DOUT * DH + 255) / 256, 256, 0, stream>>>(fc_w, fcw_b, DOUT * DH);
    gather_kernel<<<(M_ * DIN) / 256, 256, 0, stream>>>(x, emb, xe);

    gemm_bt_bias<<<dim3(M_ / 128, G3 / 128), 256, 0, stream>>>(
        xe, wih_b, b_ih, gi, M_, G3, DIN);

    gru_persistent<<<NBLK, 512, 0, stream>>>(gi, whh_b, b_hh, hs, flags);

    fc_logsoftmax<<<M_ / 64, 256, 0, stream>>>(hs, fcw_b, fc_b, out);
}

// Round 6
// 1764.415 us; speedup vs baseline: 1.1753x; 1.1753x over previous
//
#include <hip/hip_runtime.h>
#include <stdint.h>
#include <math.h>

typedef short short8 __attribute__((ext_vector_type(8)));
typedef float floatx4 __attribute__((ext_vector_type(4)));

#define MFMA(a, b, c) __builtin_amdgcn_mfma_f32_16x16x32_bf16((a), (b), (c), 0, 0, 0)

#define B_   64
#define S_   256
#define DIN  512
#define DH   1024
#define G3   3072
#define DOUT 64
#define M_   (B_ * S_)  // 16384
#define NBLK 128        // persistent blocks: 64 col-chunks x 2 batch halves
#define NFLAG (S_ * 2 * 128)  // [s][mh][jc*2+mt] ready flags

#define AGENT_LD_U32(p) __hip_atomic_load((p), __ATOMIC_RELAXED, __HIP_MEMORY_SCOPE_AGENT)
#define AGENT_ST_U32(p, v) __hip_atomic_store((p), (v), __ATOMIC_RELAXED, __HIP_MEMORY_SCOPE_AGENT)

__device__ __forceinline__ unsigned short f2bf(float f) {
    union { float f; uint32_t u; } v; v.f = f;
    uint32_t u = v.u;
    uint32_t r = (u + 0x7fffu + ((u >> 16) & 1u)) >> 16;  // RNE
    return (unsigned short)r;
}
__device__ __forceinline__ float bf2f(unsigned short s) {
    union { uint32_t u; float f; } v; v.u = ((uint32_t)s) << 16; return v.f;
}
__device__ __forceinline__ short8 ld8(const unsigned short* p) {
    return *reinterpret_cast<const short8*>(p);
}
__device__ __forceinline__ float fast_sigmoid(float x) {
    return 1.f / (1.f + __expf(-x));
}
__device__ __forceinline__ float fast_tanh(float x) {
    return 1.f - 2.f / (__expf(2.f * x) + 1.f);
}

// ---------------- elementwise: fp32 -> bf16 cast ----------------
__global__ void cast_bf16_kernel(const float* __restrict__ src,
                                 unsigned short* __restrict__ dst, int n) {
    int i = blockIdx.x * 256 + threadIdx.x;
    if (i < n) dst[i] = f2bf(src[i]);
}

// ---------------- zero the flag region (ws is poisoned 0xAA!) ----------------
__global__ void init_flags_kernel(unsigned int* flags) {
    int i = blockIdx.x * 256 + threadIdx.x;
    if (i < NFLAG) flags[i] = 0u;
}

// ---------------- embedding gather into [s*64+b][512] bf16 ----------------
__global__ void gather_kernel(const int* __restrict__ x, const float* __restrict__ emb,
                              unsigned short* __restrict__ xe) {
    int g = blockIdx.x * 256 + threadIdx.x;  // 16384*512 total
    int m = g >> 9;          // row = s*64+b
    int k = g & 511;
    int s = m >> 6, b = m & 63;
    int tok = x[b * S_ + s];
    xe[(size_t)m * DIN + k] = f2bf(emb[(size_t)tok * DIN + k]);
}

// ---------------- bt-GEMM: C[M,N] bf16 = A[M,K] @ W[N,K]^T + bias ----------------
__global__ __launch_bounds__(256) void gemm_bt_bias(
        const unsigned short* __restrict__ A, const unsigned short* __restrict__ W,
        const float* __restrict__ bias, unsigned short* __restrict__ C,
        int M, int N, int K) {
    __shared__ __align__(16) unsigned short As[128 * 32];
    __shared__ __align__(16) unsigned short Ws[128 * 32];
    int tid = threadIdx.x;
    int lane = tid & 63, wv = tid >> 6;
    int wm = wv >> 1, wn = wv & 1;
    int q = lane >> 4, l15 = lane & 15;
    int bm = blockIdx.x, bn = blockIdx.y;

    floatx4 acc[4][4];
    floatx4 z = {0.f, 0.f, 0.f, 0.f};
    for (int i = 0; i < 4; i++) for (int j = 0; j < 4; j++) acc[i][j] = z;

    int row_s = tid >> 1;
    int col_s = (tid & 1) * 16;
    const unsigned short* Ab = A + (size_t)(bm * 128 + row_s) * K + col_s;
    const unsigned short* Wb = W + (size_t)(bn * 128 + row_s) * K + col_s;
    unsigned short* AsW = &As[row_s * 32 + col_s];
    unsigned short* WsW = &Ws[row_s * 32 + col_s];

    for (int k0 = 0; k0 < K; k0 += 32) {
        __syncthreads();
        *reinterpret_cast<short8*>(AsW)     = ld8(Ab + k0);
        *reinterpret_cast<short8*>(AsW + 8) = ld8(Ab + k0 + 8);
        *reinterpret_cast<short8*>(WsW)     = ld8(Wb + k0);
        *reinterpret_cast<short8*>(WsW + 8) = ld8(Wb + k0 + 8);
        __syncthreads();
        short8 af[4], wf[4];
        for (int t = 0; t < 4; t++) {
            af[t] = ld8(&As[(wm * 64 + t * 16 + l15) * 32 + q * 8]);
            wf[t] = ld8(&Ws[(wn * 64 + t * 16 + l15) * 32 + q * 8]);
        }
        for (int i = 0; i < 4; i++)
            for (int j = 0; j < 4; j++)
                acc[i][j] = MFMA(af[i], wf[j], acc[i][j]);
    }
    for (int i = 0; i < 4; i++) {
        int row = bm * 128 + wm * 64 + i * 16 + q * 4;
        for (int j = 0; j < 4; j++) {
            int col = bn * 128 + wn * 64 + j * 16 + l15;
            float bv = bias[col];
            for (int r = 0; r < 4; r++)
                C[(size_t)(row + r) * N + col] = f2bf(acc[i][j][r] + bv);
        }
    }
}

// ---------------- persistent GRU recurrence ----------------
// 128 blocks x 512 thr (8 waves). Block = (jc: 16 h-cols, all 3 gates) x (mh: 32
// batch rows). Wave = (mt: 16-row tile) x (kh: 256-wide K quarter).
// Serial-chain design: h stores are sc1 (write-through to MALL); each GATE WAVE
// drains its own vmcnt and publishes its own flag (no block barrier in the
// publish path). Consumers poll 32 flags (coalesced) then read hs with NORMAL
// b128 loads: addresses are fresh per step so no staleness is possible, and the
// per-XCD L2 turns the 64KB broadcast into one MALL fetch per XCD.
// One __syncthreads per step (red[] double-buffered).
__global__ __launch_bounds__(512, 2) void gru_persistent(
        const unsigned short* __restrict__ gi,   // [256][64][3072] bf16 (incl b_ih)
        const unsigned short* __restrict__ whh,  // [3072][1024] bf16
        const float* __restrict__ b_hh,          // [3072]
        unsigned short* __restrict__ hs,         // [256][64][1024] bf16
        unsigned int* flags) {                   // [256][2][128]: [s][mh][jc*2+mt]
    const int tid = threadIdx.x;
    const int lane = tid & 63, wv = tid >> 6;
    const int mt = wv & 1, kh = wv >> 1;         // kh 0..3
    const int q = lane >> 4, l15 = lane & 15;
    const int jc = blockIdx.x >> 1, mh = blockIdx.x & 1;
    const int j = jc * 16 + l15;                 // h-col 0..1023
    const int brow0 = mh * 32 + mt * 16;         // wave's 16 batch rows

    __shared__ float red[2][3][2][3][64][4];     // [s&1][kh-1][mt][g][lane][r] = 36 KB

    // ---- register-resident weight fragments: rows {j, 1024+j, 2048+j}, K quarter kh ----
    short8 wfrag[3][8];
#pragma unroll
    for (int g = 0; g < 3; g++)
#pragma unroll
        for (int kk = 0; kk < 8; kk++)
            wfrag[g][kk] = ld8(whh + (size_t)(g * 1024 + j) * DH + kh * 256 + kk * 32 + q * 8);

    float bhr = 0.f, bhz = 0.f, bhn = 0.f;
    float hreg[4];
    float gir[4], giz[4], gin[4];
    if (kh == 0) {
        bhr = b_hh[j]; bhz = b_hh[1024 + j]; bhn = b_hh[2048 + j];
#pragma unroll
        for (int r = 0; r < 4; r++) {
            hreg[r] = 0.f;
            int b = brow0 + q * 4 + r;           // initial gi prefetch (s=0)
            gir[r] = bf2f(gi[(size_t)b * G3 + j]);
            giz[r] = bf2f(gi[(size_t)b * G3 + 1024 + j]);
            gin[r] = bf2f(gi[(size_t)b * G3 + 2048 + j]);
        }
    }

    for (int s = 0; s < S_; s++) {
        const int pb = s & 1;
        // ---- MFMA phase: gh partials for this K quarter ----
        floatx4 zf = {0.f, 0.f, 0.f, 0.f};
        floatx4 acc[3] = {zf, zf, zf};
        if (s > 0) {
            // wait for the 32 producer flags of my K quarter (step s-1, my mh half)
            const unsigned int* fp =
                flags + (((s - 1) << 1) + mh) * 128 + kh * 32 + (lane & 31);
            while (!__all(AGENT_LD_U32(fp) != 0u)) {}
            asm volatile("" ::: "memory");

            // NORMAL vector loads: fresh addresses, L2-shared across blocks on XCD
            const unsigned short* hp =
                hs + ((size_t)(s - 1) * B_ + (brow0 + l15)) * DH + kh * 256 + q * 8;
#pragma unroll
            for (int kk = 0; kk < 8; kk++) {
                short8 a = ld8(hp + kk * 32);
#pragma unroll
                for (int g = 0; g < 3; g++)
                    acc[g] = MFMA(a, wfrag[g][kk], acc[g]);
            }
        }

        // ---- cross-wave K reduction (vector LDS writes) ----
        if (kh > 0) {
#pragma unroll
            for (int g = 0; g < 3; g++)
                *reinterpret_cast<floatx4*>(&red[pb][kh - 1][mt][g][lane][0]) = acc[g];
        }
        __syncthreads();

        // ---- gate phase (the two kh==0 waves) ----
        if (kh == 0) {
#pragma unroll
            for (int p = 0; p < 3; p++)
#pragma unroll
                for (int g = 0; g < 3; g++) {
                    floatx4 v = *reinterpret_cast<const floatx4*>(&red[pb][p][mt][g][lane][0]);
                    acc[g] += v;
                }
            uint32_t* ho32 = (uint32_t*)(hs + (size_t)s * B_ * DH);
#pragma unroll
            for (int r = 0; r < 4; r++) {
                int b = brow0 + q * 4 + r;
                float rg = fast_sigmoid(gir[r] + acc[0][r] + bhr);
                float zg = fast_sigmoid(giz[r] + acc[1][r] + bhz);
                float ng = fast_tanh(gin[r] + rg * (acc[2][r] + bhn));
                float h = (1.f - zg) * ng + zg * hreg[r];
                hreg[r] = h;
                // pack bf16 pair across adjacent lanes (cols j, j+1), even lane stores u32
                float hnb = __shfl_xor(h, 1);
                if ((l15 & 1) == 0) {
                    uint32_t pk = (uint32_t)f2bf(h) | ((uint32_t)f2bf(hnb) << 16);
                    AGENT_ST_U32(&ho32[((size_t)b * DH + j) >> 1], pk);
                }
            }
            if (s + 1 < S_) {
                // own-wave drain: sc1 stores are at the MALL once vmcnt==0 (no wbl2
                // needed - nothing dirty in L2). Then publish this wave's flag.
                asm volatile("" ::: "memory");
                __builtin_amdgcn_s_waitcnt(0);
                asm volatile("" ::: "memory");
                if (lane == 0)
                    AGENT_ST_U32(&flags[((s << 1) + mh) * 128 + jc * 2 + mt], 1u);
                // gi prefetch for s+1 AFTER publish: HBM latency off the chain
                const unsigned short* gp = gi + (size_t)(s + 1) * B_ * G3;
#pragma unroll
                for (int r = 0; r < 4; r++) {
                    int b = brow0 + q * 4 + r;
                    gir[r] = bf2f(gp[(size_t)b * G3 + j]);
                    giz[r] = bf2f(gp[(size_t)b * G3 + 1024 + j]);
                    gin[r] = bf2f(gp[(size_t)b * G3 + 2048 + j]);
                }
            }
        }
    }
}

// ---------------- FC + log_softmax, fused ----------------
__global__ __launch_bounds__(256) void fc_logsoftmax(
        const unsigned short* __restrict__ hs,    // [16384][1024] bf16, row = s*64+b
        const unsigned short* __restrict__ fcw,   // [64][1024] bf16
        const float* __restrict__ fcb,            // [64]
        float* __restrict__ out) {                // [B][S][64]
    int tid = threadIdx.x;
    int lane = tid & 63, mt = tid >> 6;
    int q = lane >> 4, l15 = lane & 15;
    int r0 = blockIdx.x * 64;

    floatx4 acc[4];
    floatx4 z = {0.f, 0.f, 0.f, 0.f};
    for (int nt = 0; nt < 4; nt++) acc[nt] = z;

    const unsigned short* Ap = hs + (size_t)(r0 + mt * 16 + l15) * DH + q * 8;
    const unsigned short* Wp = fcw + (size_t)l15 * DH + q * 8;
    for (int k0 = 0; k0 < DH; k0 += 32) {
        short8 a = ld8(Ap + k0);
        for (int nt = 0; nt < 4; nt++)
            acc[nt] = MFMA(a, ld8(Wp + (size_t)nt * 16 * DH + k0), acc[nt]);
    }

    float bv[4];
    for (int nt = 0; nt < 4; nt++) bv[nt] = fcb[nt * 16 + l15];

    for (int r = 0; r < 4; r++) {
        float v[4];
        for (int nt = 0; nt < 4; nt++) v[nt] = acc[nt][r] + bv[nt];
        float m = fmaxf(fmaxf(v[0], v[1]), fmaxf(v[2], v[3]));
        for (int off = 1; off < 16; off <<= 1) m = fmaxf(m, __shfl_xor(m, off));
        float se = __expf(v[0] - m) + __expf(v[1] - m) + __expf(v[2] - m) + __expf(v[3] - m);
        for (int off = 1; off < 16; off <<= 1) se += __shfl_xor(se, off);
        float L = logf(se);
        int row = r0 + mt * 16 + q * 4 + r;  // = s*64 + b
        int srow = row >> 6, brow = row & 63;
        float* op = out + (size_t)(brow * S_ + srow) * DOUT;
        for (int nt = 0; nt < 4; nt++) op[nt * 16 + l15] = v[nt] - m - L;
    }
}

extern "C" void kernel_launch(void* const* d_in, const int* in_sizes, int n_in,
                              void* d_out, int out_size, void* d_ws, size_t ws_size,
                              hipStream_t stream) {
    const int*   x    = (const int*)d_in[0];
    const float* emb  = (const float*)d_in[1];
    const float* w_ih = (const float*)d_in[2];
    const float* w_hh = (const float*)d_in[3];
    const float* b_ih = (const float*)d_in[4];
    const float* b_hh = (const float*)d_in[5];
    const float* fc_w = (const float*)d_in[6];
    const float* fc_b = (const float*)d_in[7];
    float* out = (float*)d_out;

    char* p = (char*)d_ws;
    unsigned int*   flags = (unsigned int*)p;   p += NFLAG * 4;              // 256 KB
    unsigned short* xe    = (unsigned short*)p; p += (size_t)M_ * DIN * 2;   // 16 MB
    unsigned short* gi    = (unsigned short*)p; p += (size_t)M_ * G3 * 2;    // 100.7 MB
    unsigned short* wih_b = (unsigned short*)p; p += (size_t)G3 * DIN * 2;   // 3 MB
    unsigned short* whh_b = (unsigned short*)p; p += (size_t)G3 * DH * 2;    // 6.3 MB
    unsigned short* fcw_b = (unsigned short*)p; p += (size_t)DOUT * DH * 2;  // 128 KB
    unsigned short* hs    = (unsigned short*)p; p += (size_t)M_ * DH * 2;    // 33.6 MB

    init_flags_kernel<<<(NFLAG + 255) / 256, 256, 0, stream>>>(flags);
    cast_bf16_kernel<<<(G3 * DIN + 255) / 256, 256, 0, stream>>>(w_ih, wih_b, G3 * DIN);
    cast_bf16_kernel<<<(G3 * DH + 255) / 256, 256, 0, stream>>>(w_hh, whh_b, G3 * DH);
    cast_bf16_kernel<<<(DOUT * DH + 255) / 256, 256, 0, stream>>>(fc_w, fcw_b, DOUT * DH);
    gather_kernel<<<(M_ * DIN) / 256, 256, 0, stream>>>(x, emb, xe);

    gemm_bt_bias<<<dim3(M_ / 128, G3 / 128), 256, 0, stream>>>(
        xe, wih_b, b_ih, gi, M_, G3, DIN);

    gru_persistent<<<NBLK, 512, 0, stream>>>(gi, whh_b, b_hh, hs, flags);

    fc_logsoftmax<<<M_ / 64, 256, 0, stream>>>(hs, fcw_b, fc_b, out);
}